// Round 4
// baseline (1223.802 us; speedup 1.0000x reference)
//
#include <hip/hip_runtime.h>
#include <hip/hip_bf16.h>

#define BGRAPH 16384
#define NPG 9
#define RANK 512
#define EPER 12
#define NNODE (BGRAPH*NPG)      // 147456
#define GPB 16                  // graphs per block
#define BM (GPB*NPG)            // 144 rows per block
#define BK 32                   // K-chunk (one MFMA k-step)
#define NKC (RANK/BK)           // 16
#define LEPS 1e-5f

typedef unsigned short u16;
typedef unsigned int u32;
typedef __attribute__((ext_vector_type(8))) short s16x8;
typedef __attribute__((ext_vector_type(4))) float f32x4;

static __device__ __forceinline__ float bf2f(u16 u){
    union { u32 i; float f; } v; v.i = ((u32)u) << 16; return v.f;
}
static __device__ __forceinline__ u16 f2bf(float f){
    union { float f; u32 i; } v; v.f = f;
    u32 r = v.i + 0x7FFFu + ((v.i >> 16) & 1u);   // RNE
    return (u16)(r >> 16);
}

// ---- W repack into B-fragment order (bf16) ----
// Wp[((kc*32 + c)*64 + l)*8 + j] = W[kc*32 + (l>>4)*8 + j][c*16 + (l&15)]
__global__ void k_repack(const float* __restrict__ Ws, u16* __restrict__ Wp){
    int t = blockIdx.x*256 + threadIdx.x;          // 3*512*512 total
    int layer = t >> 18;
    int r = t & 262143;
    int j = r & 7, l = (r>>3)&63, c = (r>>9)&31, kb = r>>14;
    int k = kb*32 + (l>>4)*8 + j;
    int col = c*16 + (l&15);
    Wp[t] = f2bf(Ws[(size_t)layer*262144 + (size_t)k*512 + col]);
}

// ---- everything else, fused; h lives in LDS for all 3 layers ----
__launch_bounds__(512, 2)
__global__ void k_all(const int* __restrict__ feat, const int* __restrict__ src,
                      const int* __restrict__ dst, const float* __restrict__ emb,
                      const u16* __restrict__ Wp,
                      const float* __restrict__ bs, const float* __restrict__ gam,
                      const float* __restrict__ bet,
                      const float* __restrict__ w_out, const float* __restrict__ b_out,
                      float* __restrict__ out)
{
    // h[row][k] bf16 stored swizzled: 16B slot s -> s ^ (row&7)
    __shared__ __align__(16) u16 h[BM*RANK];      // 147456 B
    __shared__ __align__(16) u16 m_t[BM*BK];      // 9216 B; epilogue overlays red_s/red_q here
    __shared__ float csr_w[GPB*EPER];
    __shared__ u16   csr_src[GPB*EPER];
    __shared__ u16   csr_start[BM+2];
    __shared__ float s_inn[BM];
    __shared__ float s_onorm[BM];
    __shared__ float s_mu[BM], s_rs[BM];
    __shared__ int   s_feat[BM];
    __shared__ int   s_probe[8];
    __shared__ int   s_flags[2];

    const int t = threadIdx.x;
    const int lane = t & 63;
    const int w = t >> 6;
    const int g0 = blockIdx.x * GPB;
    const int row0 = g0 * NPG;

    // ---- dtype detection (int32 vs int64 buffers), fault-proof ----
    if (t < 8) s_probe[t] = feat[2*t + 1];        // high words if int64
    __syncthreads();
    if (t == 0){
        int o = 0;
        #pragma unroll
        for (int i=0;i<8;i++) o |= s_probe[i];
        s_flags[0] = (o == 0);                    // feat is int64
        int v = src[EPER*BGRAPH - 1];             // int32: >=147447; int64: 0 (high word)
        s_flags[1] = (v < (BGRAPH-1)*NPG);        // src/dst are int64
    }
    __syncthreads();
    const int f64 = s_flags[0], i64 = s_flags[1];

    // ---- feat stage + per-block CSR (layer-invariant) ----
    if (t < BM){
        int n = row0 + t;
        int f = f64 ? feat[2*n] : feat[n];
        s_feat[t] = (f < 0) ? 0 : (f > 5 ? 5 : f);
    }
    if (t < GPB){
        int g = g0 + t;
        int sl[EPER], dl[EPER];
        #pragma unroll
        for (int j=0;j<EPER;j++){
            int e = g*EPER + j;
            int sv = (i64 ? src[2*e] : src[e]) - g*NPG;
            int dv = (i64 ? dst[2*e] : dst[e]) - g*NPG;
            sl[j] = sv<0?0:(sv>8?8:sv);
            dl[j] = dv<0?0:(dv>8?8:dv);
        }
        #pragma unroll
        for (int i=0;i<NPG;i++){
            int co=0, ci=0;
            #pragma unroll
            for (int j=0;j<EPER;j++){ co += (sl[j]==i); ci += (dl[j]==i); }
            s_onorm[t*NPG+i] = rsqrtf((float)(co>0?co:1));
            s_inn [t*NPG+i] = rsqrtf((float)(ci>0?ci:1));
        }
        int p = t*EPER;
        #pragma unroll
        for (int d=0; d<NPG; d++){
            csr_start[t*NPG + d] = (u16)p;
            #pragma unroll
            for (int j=0;j<EPER;j++){
                if (dl[j]==d){
                    csr_src[p] = (u16)(t*NPG + sl[j]);
                    csr_w[p]   = s_onorm[t*NPG + sl[j]];
                    p++;
                }
            }
        }
    }
    if (t == 0) csr_start[BM] = (u16)(GPB*EPER);
    __syncthreads();

    // ---- embedding gather -> h (bf16, swizzled) ----
    for (int idx = t; idx < BM*64; idx += 512){
        int row = idx >> 6, slot = idx & 63;
        const float4* e = reinterpret_cast<const float4*>(emb + (size_t)s_feat[row]*RANK + slot*8);
        float4 a = e[0], b = e[1];
        uint4 o;
        o.x = (u32)f2bf(a.x) | ((u32)f2bf(a.y)<<16);
        o.y = (u32)f2bf(a.z) | ((u32)f2bf(a.w)<<16);
        o.z = (u32)f2bf(b.x) | ((u32)f2bf(b.y)<<16);
        o.w = (u32)f2bf(b.z) | ((u32)f2bf(b.w)<<16);
        int sl2 = slot ^ (row & 7);
        *reinterpret_cast<uint4*>(h + row*RANK + sl2*8) = o;
    }

    const int lr = lane & 15, hi = lane >> 4;
    const int kp = lane & 15, rsel = lane >> 4;   // aggregation lane roles

    for (int L=0; L<3; L++){
        const u16* WpL = Wp + (size_t)L*262144;
        f32x4 acc[9][4];
        #pragma unroll
        for (int r=0;r<9;r++)
            #pragma unroll
            for (int cc=0;cc<4;cc++)
                #pragma unroll
                for (int q=0;q<4;q++) acc[r][cc][q] = 0.f;

        __syncthreads();   // h (embed or previous layer) ready

        for (int kc=0; kc<NKC; kc++){
            // a) aggregate this 32-col chunk into m_t (bf16, swizzled)
            //    4 rows x 16 k-pairs per wave-instruction; 5 iters covers 18 rows/wave
            #pragma unroll
            for (int i=0;i<5;i++){
                int row = w*18 + i*4 + rsel;
                if (i<4 || rsel<2){
                    float a0=0.f, a1=0.f;
                    int e0 = csr_start[row], e1 = csr_start[row+1];
                    int k0 = kc*32 + kp*2;
                    for (int e=e0; e<e1; e++){
                        int srow = (int)csr_src[e]; float wt = csr_w[e];
                        int slot = (k0>>3) ^ (srow & 7);
                        u32 v = *reinterpret_cast<const u32*>(h + srow*RANK + slot*8 + (k0&7));
                        a0 += wt * bf2f((u16)(v & 0xffffu));
                        a1 += wt * bf2f((u16)(v >> 16));
                    }
                    float fin = s_inn[row];
                    a0 *= fin; a1 *= fin;
                    int ms = (kp>>2) ^ ((row>>1)&3);
                    u32 o = (u32)f2bf(a0) | ((u32)f2bf(a1)<<16);
                    *reinterpret_cast<u32*>(m_t + row*BK + ms*8 + ((kp*2)&7)) = o;
                }
            }
            __syncthreads();
            // b) MFMA: wave w owns cols [w*64, w*64+64)
            s16x8 af[9];
            #pragma unroll
            for (int r=0;r<9;r++){
                int rowa = r*16 + lr;
                int ms = hi ^ ((rowa>>1)&3);
                af[r] = *reinterpret_cast<const s16x8*>(m_t + rowa*BK + ms*8);
            }
            #pragma unroll
            for (int cc=0;cc<4;cc++){
                s16x8 bf = *reinterpret_cast<const s16x8*>(WpL + (size_t)(((kc*32 + (w*4+cc))*64 + lane)*8));
                #pragma unroll
                for (int r=0;r<9;r++)
                    acc[r][cc] = __builtin_amdgcn_mfma_f32_16x16x32_bf16(af[r], bf, acc[r][cc], 0, 0, 0);
            }
            __syncthreads();
        }

        // ---- epilogue: bias + LN + ReLU -> write h back (bf16, swizzled) ----
        const float* bias = bs + L*RANK;
        const float* gmp  = gam + L*RANK;
        const float* btp  = bet + L*RANK;
        float b4[4], g4[4], bt4[4];
        #pragma unroll
        for (int cc=0;cc<4;cc++){
            int col = w*64 + cc*16 + lr;
            b4[cc] = bias[col]; g4[cc] = gmp[col]; bt4[cc] = btp[col];
        }
        #pragma unroll
        for (int r=0;r<9;r++)
            #pragma unroll
            for (int cc=0;cc<4;cc++)
                #pragma unroll
                for (int q=0;q<4;q++) acc[r][cc][q] += b4[cc];

        float* red_s = reinterpret_cast<float*>(m_t);   // overlay (m_t dead after k-loop barrier)
        float* red_q = red_s + BM*8;
        #pragma unroll
        for (int r=0;r<9;r++){
            #pragma unroll
            for (int q=0;q<4;q++){
                float s=0.f, qq=0.f;
                #pragma unroll
                for (int cc=0;cc<4;cc++){ float x = acc[r][cc][q]; s += x; qq += x*x; }
                #pragma unroll
                for (int mm=1;mm<16;mm<<=1){ s += __shfl_xor(s, mm, 64); qq += __shfl_xor(qq, mm, 64); }
                if (lr==0){ int row = r*16 + hi*4 + q; red_s[row*8+w]=s; red_q[row*8+w]=qq; }
            }
        }
        __syncthreads();
        if (t < BM){
            float s=0.f, qq=0.f;
            #pragma unroll
            for (int i=0;i<8;i++){ s += red_s[t*8+i]; qq += red_q[t*8+i]; }
            float mu = s * (1.f/RANK);
            float var = qq*(1.f/RANK) - mu*mu;
            s_mu[t] = mu; s_rs[t] = rsqrtf(var + LEPS);
        }
        __syncthreads();
        #pragma unroll
        for (int r=0;r<9;r++){
            #pragma unroll
            for (int q=0;q<4;q++){
                int row = r*16 + hi*4 + q;
                float mu = s_mu[row], rs = s_rs[row];
                #pragma unroll
                for (int cc=0;cc<4;cc++){
                    int col = w*64 + cc*16 + lr;
                    float y = (acc[r][cc][q]-mu)*rs*g4[cc] + bt4[cc];
                    y = fmaxf(y, 0.f);
                    int slot = col >> 3;
                    int sl2 = slot ^ (row & 7);
                    h[row*RANK + sl2*8 + (col&7)] = f2bf(y);
                }
            }
        }
    }
    __syncthreads();

    // ---- final dot: graph g's first node . w_out ----
    #pragma unroll
    for (int gi=0; gi<2; gi++){
        int g = w*2 + gi;                 // 16 graphs / 8 waves
        int row = g*NPG;
        int sl2 = lane ^ (row & 7);
        s16x8 hv = *reinterpret_cast<const s16x8*>(h + row*RANK + sl2*8);
        const float4* wv = reinterpret_cast<const float4*>(w_out + lane*8);
        float4 w0 = wv[0], w1 = wv[1];
        float a = bf2f((u16)hv[0])*w0.x + bf2f((u16)hv[1])*w0.y
                + bf2f((u16)hv[2])*w0.z + bf2f((u16)hv[3])*w0.w
                + bf2f((u16)hv[4])*w1.x + bf2f((u16)hv[5])*w1.y
                + bf2f((u16)hv[6])*w1.z + bf2f((u16)hv[7])*w1.w;
        #pragma unroll
        for (int mm=1;mm<64;mm<<=1) a += __shfl_xor(a, mm, 64);
        if (lane==0) out[g0 + g] = a + b_out[0];
    }
}

extern "C" void kernel_launch(void* const* d_in, const int* in_sizes, int n_in,
                              void* d_out, int out_size, void* d_ws, size_t ws_size,
                              hipStream_t stream){
    (void)in_sizes; (void)n_in; (void)out_size; (void)ws_size;
    const int*   feat  = (const int*)d_in[0];
    const int*   src   = (const int*)d_in[1];
    const int*   dst   = (const int*)d_in[2];
    const float* emb   = (const float*)d_in[3];
    const float* Ws    = (const float*)d_in[4];
    const float* bs    = (const float*)d_in[5];
    const float* gam   = (const float*)d_in[6];
    const float* bet   = (const float*)d_in[7];
    const float* w_out = (const float*)d_in[8];
    const float* b_out = (const float*)d_in[9];
    float* out = (float*)d_out;

    u16* Wp = (u16*)d_ws;   // 3*512*512*2 = 1.5 MB — only ws use

    k_repack<<<dim3(3*RANK*RANK/256), dim3(256), 0, stream>>>(Ws, Wp);
    k_all<<<dim3(BGRAPH/GPB), dim3(512), 0, stream>>>(feat, src, dst, emb, Wp,
        bs, gam, bet, w_out, b_out, out);
}

// Round 6
// 1220.656 us; speedup vs baseline: 1.0026x; 1.0026x over previous
//
#include <hip/hip_runtime.h>
#include <hip/hip_bf16.h>

#define BGRAPH 16384
#define NPG 9
#define RANK 512
#define EPER 12
#define NNODE (BGRAPH*NPG)      // 147456
#define GPB 16                  // graphs per block
#define BM (GPB*NPG)            // 144 rows per block
#define LEPS 1e-5f

typedef unsigned short u16;
typedef unsigned int u32;
typedef __attribute__((ext_vector_type(8))) short s16x8;
typedef __attribute__((ext_vector_type(4))) float f32x4;

static __device__ __forceinline__ float bf2f(u16 u){
    union { u32 i; float f; } v; v.i = ((u32)u) << 16; return v.f;
}
static __device__ __forceinline__ u16 f2bf(float f){
    union { float f; u32 i; } v; v.f = f;
    u32 r = v.i + 0x7FFFu + ((v.i >> 16) & 1u);   // RNE
    return (u16)(r >> 16);
}

// ---- W repack into B-fragment order (bf16), shared by both paths ----
// Wp[((kb*32 + c)*64 + l)*8 + j] = W[kb*32 + (l>>4)*8 + j][c*16 + (l&15)]
__global__ void k_repack(const float* __restrict__ Ws, u16* __restrict__ Wp){
    int t = blockIdx.x*256 + threadIdx.x;          // 3*512*512 total
    int layer = t >> 18;
    int r = t & 262143;
    int j = r & 7, l = (r>>3)&63, c = (r>>9)&31, kb = r>>14;
    int k = kb*32 + (l>>4)*8 + j;
    int col = c*16 + (l&15);
    Wp[t] = f2bf(Ws[(size_t)layer*262144 + (size_t)k*512 + col]);
}

// ============================ FAST PATH ============================

// per-graph dense aggregation matrix A[d][s] = in_norm[d]*out_norm[s]*mult(s->d)
__global__ void k_prep(const int* __restrict__ src, const int* __restrict__ dst,
                       float* __restrict__ Ag){
    int g = blockIdx.x*256 + threadIdx.x;
    if (g >= BGRAPH) return;
    // dtype probe: last int32 word is >=147447 if int32, 0 (high word) if int64
    int i64 = (src[EPER*BGRAPH - 1] < (BGRAPH-1)*NPG);
    int sl[EPER], dl[EPER];
    #pragma unroll
    for (int j=0;j<EPER;j++){
        int e = g*EPER + j;
        int sv = (i64 ? src[2*e] : src[e]) - g*NPG;
        int dv = (i64 ? dst[2*e] : dst[e]) - g*NPG;
        sl[j] = sv<0?0:(sv>8?8:sv);
        dl[j] = dv<0?0:(dv>8?8:dv);
    }
    float onorm[NPG], inorm[NPG];
    #pragma unroll
    for (int i=0;i<NPG;i++){
        int co=0, ci=0;
        #pragma unroll
        for (int j=0;j<EPER;j++){ co += (sl[j]==i); ci += (dl[j]==i); }
        onorm[i] = rsqrtf((float)(co>0?co:1));
        inorm[i] = rsqrtf((float)(ci>0?ci:1));
    }
    float* Arow = Ag + (size_t)g*81;
    #pragma unroll
    for (int d=0; d<NPG; d++){
        #pragma unroll
        for (int s=0; s<NPG; s++){
            int c = 0;
            #pragma unroll
            for (int j=0;j<EPER;j++) c += (dl[j]==d) & (sl[j]==s);
            Arow[d*9+s] = inorm[d]*onorm[s]*(float)c;
        }
    }
}

// embedding gather -> h (bf16, row-major in ws)
__global__ void k_embed(const int* __restrict__ feat, const float* __restrict__ emb,
                        u16* __restrict__ h){
    int tid = blockIdx.x*256 + threadIdx.x;        // NNODE*64 threads
    int n = tid >> 6, part = tid & 63;
    int f64 = ((feat[1]|feat[3]|feat[5]|feat[7]|feat[9]|feat[11]|feat[13]|feat[15]) == 0);
    int f = f64 ? feat[2*n] : feat[n];
    f = (f<0)?0:(f>5?5:f);
    const float4* e = reinterpret_cast<const float4*>(emb + (size_t)f*RANK + part*8);
    float4 a = e[0], b = e[1];
    uint4 o;
    o.x = (u32)f2bf(a.x) | ((u32)f2bf(a.y)<<16);
    o.y = (u32)f2bf(a.z) | ((u32)f2bf(a.w)<<16);
    o.z = (u32)f2bf(b.x) | ((u32)f2bf(b.y)<<16);
    o.w = (u32)f2bf(b.z) | ((u32)f2bf(b.w)<<16);
    *reinterpret_cast<uint4*>(h + (size_t)n*RANK + part*8) = o;
}

// fused layer: stage -> dense-A aggregate -> MFMA -> bias+LN+ReLU -> h_out
__launch_bounds__(512, 4)
__global__ void k_layer(const u16* __restrict__ h_in, u16* __restrict__ h_out,
                        const u16* __restrict__ WpL, const float* __restrict__ Ag,
                        const float* __restrict__ bias, const float* __restrict__ gamma,
                        const float* __restrict__ beta){
    __shared__ __align__(16) u16 h_lds[BM*64];     // 18432 B, 16B-slot XOR swizzled
    __shared__ __align__(16) u16 m_t[BM*64];       // 18432 B; epilogue overlays red_s/red_q
    __shared__ float A_s[GPB*81];                  // 5184 B
    __shared__ float s_mu[BM], s_rs[BM];

    const int t = threadIdx.x;
    const int lane = t & 63;
    const int w = t >> 6;
    const int g0 = blockIdx.x * GPB;
    const int row0 = g0 * NPG;

    for (int i=t; i<GPB*81; i+=512) A_s[i] = Ag[(size_t)g0*81 + i];

    f32x4 acc[9][4];
    #pragma unroll
    for (int r=0;r<9;r++)
        #pragma unroll
        for (int cc=0;cc<4;cc++)
            #pragma unroll
            for (int q=0;q<4;q++) acc[r][cc][q] = 0.f;

    const int lr = lane & 15, hi = lane >> 4;
    const int rp = lane >> 5, cp = lane & 31;      // aggregation roles
    const int col2 = cp*2;

    for (int kc=0; kc<8; kc++){
        // a) stage h chunk (64 cols) -> LDS, swizzled
        for (int idx=t; idx<BM*8; idx+=512){
            int row = idx>>3, part = idx&7;
            uint4 v = *reinterpret_cast<const uint4*>(h_in + (size_t)(row0+row)*RANK + kc*64 + part*8);
            *reinterpret_cast<uint4*>(h_lds + row*64 + (part^(row&7))*8) = v;
        }
        __syncthreads();
        // b) dense aggregation: 9 passes x 2 rows/wave, lane pair = 2 cols
        #pragma unroll
        for (int p=0;p<9;p++){
            int rr = p*2 + rp;                     // 0..17 within wave
            int d  = (rr<9) ? rr : rr-9;
            int gl = 2*w + ((rr<9) ? 0 : 1);
            int row = w*18 + rr;
            int base = row - d;                    // first row of the graph
            const float* Arow = &A_s[gl*81 + d*9];
            float a0=0.f, a1=0.f;
            #pragma unroll
            for (int s=0;s<9;s++){
                float wA = Arow[s];
                int sr = base + s;
                u32 v = *reinterpret_cast<const u32*>(
                    h_lds + sr*64 + ((col2>>3)^(sr&7))*8 + (col2&7));
                a0 += wA * bf2f((u16)(v & 0xffffu));
                a1 += wA * bf2f((u16)(v >> 16));
            }
            u32 o = (u32)f2bf(a0) | ((u32)f2bf(a1)<<16);
            *reinterpret_cast<u32*>(m_t + row*64 + ((col2>>3)^(row&7))*8 + (col2&7)) = o;
        }
        __syncthreads();
        // c) MFMA: wave w owns cols [w*64, w*64+64)
        #pragma unroll
        for (int kk=0; kk<2; kk++){
            s16x8 af[9];
            #pragma unroll
            for (int r=0;r<9;r++){
                int rowa = r*16 + lr;
                af[r] = *reinterpret_cast<const s16x8*>(
                    m_t + rowa*64 + ((kk*4+hi)^(rowa&7))*8);
            }
            #pragma unroll
            for (int cc=0;cc<4;cc++){
                s16x8 bf = *reinterpret_cast<const s16x8*>(
                    WpL + (size_t)((((kc*2+kk)*32 + (w*4+cc))*64 + lane)*8));
                #pragma unroll
                for (int r=0;r<9;r++)
                    acc[r][cc] = __builtin_amdgcn_mfma_f32_16x16x32_bf16(af[r], bf, acc[r][cc], 0, 0, 0);
            }
        }
        __syncthreads();
    }

    // epilogue: bias + LN + ReLU -> global h_out (row-major)
    float b4[4], g4[4], bt4[4];
    #pragma unroll
    for (int cc=0;cc<4;cc++){
        int col = w*64 + cc*16 + lr;
        b4[cc] = bias[col]; g4[cc] = gamma[col]; bt4[cc] = beta[col];
    }
    #pragma unroll
    for (int r=0;r<9;r++)
        #pragma unroll
        for (int cc=0;cc<4;cc++)
            #pragma unroll
            for (int q=0;q<4;q++) acc[r][cc][q] += b4[cc];

    float* red_s = reinterpret_cast<float*>(m_t);       // 4608 B
    float* red_q = red_s + BM*8;                        // 4608 B (fits in 18432)
    #pragma unroll
    for (int r=0;r<9;r++){
        #pragma unroll
        for (int q=0;q<4;q++){
            float s=0.f, qq=0.f;
            #pragma unroll
            for (int cc=0;cc<4;cc++){ float x = acc[r][cc][q]; s += x; qq += x*x; }
            #pragma unroll
            for (int mm=1;mm<16;mm<<=1){ s += __shfl_xor(s, mm, 64); qq += __shfl_xor(qq, mm, 64); }
            if (lr==0){ int row = r*16 + hi*4 + q; red_s[row*8+w]=s; red_q[row*8+w]=qq; }
        }
    }
    __syncthreads();
    if (t < BM){
        float s=0.f, qq=0.f;
        #pragma unroll
        for (int i=0;i<8;i++){ s += red_s[t*8+i]; qq += red_q[t*8+i]; }
        float mu = s * (1.f/RANK);
        float var = qq*(1.f/RANK) - mu*mu;
        s_mu[t] = mu; s_rs[t] = rsqrtf(var + LEPS);
    }
    __syncthreads();
    #pragma unroll
    for (int r=0;r<9;r++){
        #pragma unroll
        for (int q=0;q<4;q++){
            int row = r*16 + hi*4 + q;
            float mu = s_mu[row], rs = s_rs[row];
            #pragma unroll
            for (int cc=0;cc<4;cc++){
                float y = (acc[r][cc][q]-mu)*rs*g4[cc] + bt4[cc];
                y = fmaxf(y, 0.f);
                h_out[(size_t)(row0+row)*RANK + w*64 + cc*16 + lr] = f2bf(y);
            }
        }
    }
}

// output: one wave per graph
__global__ void k_out(const u16* __restrict__ h, const float* __restrict__ w_out,
                      const float* __restrict__ b_out, float* __restrict__ out){
    int lane = threadIdx.x & 63;
    int wid = threadIdx.x >> 6;
    int b = blockIdx.x*4 + wid;
    if (b >= BGRAPH) return;
    const u16* hr = h + (size_t)b*NPG*RANK;            // first node of graph
    uint4 hv = *reinterpret_cast<const uint4*>(hr + lane*8);
    const float4* wv = reinterpret_cast<const float4*>(w_out + lane*8);
    float4 w0 = wv[0], w1 = wv[1];
    float a = bf2f((u16)(hv.x&0xffff))*w0.x + bf2f((u16)(hv.x>>16))*w0.y
            + bf2f((u16)(hv.y&0xffff))*w0.z + bf2f((u16)(hv.y>>16))*w0.w
            + bf2f((u16)(hv.z&0xffff))*w1.x + bf2f((u16)(hv.z>>16))*w1.y
            + bf2f((u16)(hv.w&0xffff))*w1.z + bf2f((u16)(hv.w>>16))*w1.w;
    #pragma unroll
    for (int mm=1;mm<64;mm<<=1) a += __shfl_xor(a, mm, 64);
    if (lane==0) out[b] = a + b_out[0];
}

// ============================ SAFE PATH (R4, verified 1223us) ============================
__launch_bounds__(512, 2)
__global__ void k_all(const int* __restrict__ feat, const int* __restrict__ src,
                      const int* __restrict__ dst, const float* __restrict__ emb,
                      const u16* __restrict__ Wp,
                      const float* __restrict__ bs, const float* __restrict__ gam,
                      const float* __restrict__ bet,
                      const float* __restrict__ w_out, const float* __restrict__ b_out,
                      float* __restrict__ out)
{
    __shared__ __align__(16) u16 h[BM*RANK];
    __shared__ __align__(16) u16 m_t2[BM*32];
    __shared__ float csr_w[GPB*EPER];
    __shared__ u16   csr_src[GPB*EPER];
    __shared__ u16   csr_start[BM+2];
    __shared__ float s_inn[BM];
    __shared__ float s_onorm[BM];
    __shared__ float s_mu[BM], s_rs[BM];
    __shared__ int   s_feat[BM];
    __shared__ int   s_probe[8];
    __shared__ int   s_flags[2];

    const int t = threadIdx.x;
    const int lane = t & 63;
    const int w = t >> 6;
    const int g0 = blockIdx.x * GPB;
    const int row0 = g0 * NPG;

    if (t < 8) s_probe[t] = feat[2*t + 1];
    __syncthreads();
    if (t == 0){
        int o = 0;
        #pragma unroll
        for (int i=0;i<8;i++) o |= s_probe[i];
        s_flags[0] = (o == 0);
        int v = src[EPER*BGRAPH - 1];
        s_flags[1] = (v < (BGRAPH-1)*NPG);
    }
    __syncthreads();
    const int f64 = s_flags[0], i64 = s_flags[1];

    if (t < BM){
        int n = row0 + t;
        int f = f64 ? feat[2*n] : feat[n];
        s_feat[t] = (f < 0) ? 0 : (f > 5 ? 5 : f);
    }
    if (t < GPB){
        int g = g0 + t;
        int sl[EPER], dl[EPER];
        #pragma unroll
        for (int j=0;j<EPER;j++){
            int e = g*EPER + j;
            int sv = (i64 ? src[2*e] : src[e]) - g*NPG;
            int dv = (i64 ? dst[2*e] : dst[e]) - g*NPG;
            sl[j] = sv<0?0:(sv>8?8:sv);
            dl[j] = dv<0?0:(dv>8?8:dv);
        }
        #pragma unroll
        for (int i=0;i<NPG;i++){
            int co=0, ci=0;
            #pragma unroll
            for (int j=0;j<EPER;j++){ co += (sl[j]==i); ci += (dl[j]==i); }
            s_onorm[t*NPG+i] = rsqrtf((float)(co>0?co:1));
            s_inn [t*NPG+i] = rsqrtf((float)(ci>0?ci:1));
        }
        int p = t*EPER;
        #pragma unroll
        for (int d=0; d<NPG; d++){
            csr_start[t*NPG + d] = (u16)p;
            #pragma unroll
            for (int j=0;j<EPER;j++){
                if (dl[j]==d){
                    csr_src[p] = (u16)(t*NPG + sl[j]);
                    csr_w[p]   = s_onorm[t*NPG + sl[j]];
                    p++;
                }
            }
        }
    }
    if (t == 0) csr_start[BM] = (u16)(GPB*EPER);
    __syncthreads();

    for (int idx = t; idx < BM*64; idx += 512){
        int row = idx >> 6, slot = idx & 63;
        const float4* e = reinterpret_cast<const float4*>(emb + (size_t)s_feat[row]*RANK + slot*8);
        float4 a = e[0], b = e[1];
        uint4 o;
        o.x = (u32)f2bf(a.x) | ((u32)f2bf(a.y)<<16);
        o.y = (u32)f2bf(a.z) | ((u32)f2bf(a.w)<<16);
        o.z = (u32)f2bf(b.x) | ((u32)f2bf(b.y)<<16);
        o.w = (u32)f2bf(b.z) | ((u32)f2bf(b.w)<<16);
        int sl2 = slot ^ (row & 7);
        *reinterpret_cast<uint4*>(h + row*RANK + sl2*8) = o;
    }

    const int lr = lane & 15, hi = lane >> 4;
    const int kp = lane & 15, rsel = lane >> 4;

    for (int L=0; L<3; L++){
        const u16* WpL = Wp + (size_t)L*262144;
        f32x4 acc[9][4];
        #pragma unroll
        for (int r=0;r<9;r++)
            #pragma unroll
            for (int cc=0;cc<4;cc++)
                #pragma unroll
                for (int q=0;q<4;q++) acc[r][cc][q] = 0.f;

        __syncthreads();

        for (int kc=0; kc<16; kc++){
            #pragma unroll
            for (int i=0;i<5;i++){
                int row = w*18 + i*4 + rsel;
                if (i<4 || rsel<2){
                    float a0=0.f, a1=0.f;
                    int e0 = csr_start[row], e1 = csr_start[row+1];
                    int k0 = kc*32 + kp*2;
                    for (int e=e0; e<e1; e++){
                        int srow = (int)csr_src[e]; float wt = csr_w[e];
                        int slot = (k0>>3) ^ (srow & 7);
                        u32 v = *reinterpret_cast<const u32*>(h + srow*RANK + slot*8 + (k0&7));
                        a0 += wt * bf2f((u16)(v & 0xffffu));
                        a1 += wt * bf2f((u16)(v >> 16));
                    }
                    float fin = s_inn[row];
                    a0 *= fin; a1 *= fin;
                    int ms = (kp>>2) ^ ((row>>1)&3);
                    u32 o = (u32)f2bf(a0) | ((u32)f2bf(a1)<<16);
                    *reinterpret_cast<u32*>(m_t2 + row*32 + ms*8 + ((kp*2)&7)) = o;
                }
            }
            __syncthreads();
            s16x8 af[9];
            #pragma unroll
            for (int r=0;r<9;r++){
                int rowa = r*16 + lr;
                int ms = hi ^ ((rowa>>1)&3);
                af[r] = *reinterpret_cast<const s16x8*>(m_t2 + rowa*32 + ms*8);
            }
            #pragma unroll
            for (int cc=0;cc<4;cc++){
                s16x8 bf = *reinterpret_cast<const s16x8*>(WpL + (size_t)(((kc*32 + (w*4+cc))*64 + lane)*8));
                #pragma unroll
                for (int r=0;r<9;r++)
                    acc[r][cc] = __builtin_amdgcn_mfma_f32_16x16x32_bf16(af[r], bf, acc[r][cc], 0, 0, 0);
            }
            __syncthreads();
        }

        const float* bias = bs + L*RANK;
        const float* gmp  = gam + L*RANK;
        const float* btp  = bet + L*RANK;
        float b4[4], g4[4], bt4[4];
        #pragma unroll
        for (int cc=0;cc<4;cc++){
            int col = w*64 + cc*16 + lr;
            b4[cc] = bias[col]; g4[cc] = gmp[col]; bt4[cc] = btp[col];
        }
        #pragma unroll
        for (int r=0;r<9;r++)
            #pragma unroll
            for (int cc=0;cc<4;cc++)
                #pragma unroll
                for (int q=0;q<4;q++) acc[r][cc][q] += b4[cc];

        float* red_s = reinterpret_cast<float*>(m_t2);
        float* red_q = red_s + BM*8;   // 9216 B total == sizeof(m_t2)
        #pragma unroll
        for (int r=0;r<9;r++){
            #pragma unroll
            for (int q=0;q<4;q++){
                float s=0.f, qq=0.f;
                #pragma unroll
                for (int cc=0;cc<4;cc++){ float x = acc[r][cc][q]; s += x; qq += x*x; }
                #pragma unroll
                for (int mm=1;mm<16;mm<<=1){ s += __shfl_xor(s, mm, 64); qq += __shfl_xor(qq, mm, 64); }
                if (lr==0){ int row = r*16 + hi*4 + q; red_s[row*8+w]=s; red_q[row*8+w]=qq; }
            }
        }
        __syncthreads();
        if (t < BM){
            float s=0.f, qq=0.f;
            #pragma unroll
            for (int i=0;i<8;i++){ s += red_s[t*8+i]; qq += red_q[t*8+i]; }
            float mu = s * (1.f/RANK);
            float var = qq*(1.f/RANK) - mu*mu;
            s_mu[t] = mu; s_rs[t] = rsqrtf(var + LEPS);
        }
        __syncthreads();
        #pragma unroll
        for (int r=0;r<9;r++){
            #pragma unroll
            for (int q=0;q<4;q++){
                int row = r*16 + hi*4 + q;
                float mu = s_mu[row], rs = s_rs[row];
                #pragma unroll
                for (int cc=0;cc<4;cc++){
                    int col = w*64 + cc*16 + lr;
                    float y = (acc[r][cc][q]-mu)*rs*g4[cc] + bt4[cc];
                    y = fmaxf(y, 0.f);
                    int slot = col >> 3;
                    int sl2 = slot ^ (row & 7);
                    h[row*RANK + sl2*8 + (col&7)] = f2bf(y);
                }
            }
        }
    }
    __syncthreads();

    #pragma unroll
    for (int gi=0; gi<2; gi++){
        int g = w*2 + gi;
        int row = g*NPG;
        int sl2 = lane ^ (row & 7);
        s16x8 hv = *reinterpret_cast<const s16x8*>(h + row*RANK + sl2*8);
        const float4* wv = reinterpret_cast<const float4*>(w_out + lane*8);
        float4 w0 = wv[0], w1 = wv[1];
        float a = bf2f((u16)hv[0])*w0.x + bf2f((u16)hv[1])*w0.y
                + bf2f((u16)hv[2])*w0.z + bf2f((u16)hv[3])*w0.w
                + bf2f((u16)hv[4])*w1.x + bf2f((u16)hv[5])*w1.y
                + bf2f((u16)hv[6])*w1.z + bf2f((u16)hv[7])*w1.w;
        #pragma unroll
        for (int mm=1;mm<64;mm<<=1) a += __shfl_xor(a, mm, 64);
        if (lane==0) out[g0 + g] = a + b_out[0];
    }
}

extern "C" void kernel_launch(void* const* d_in, const int* in_sizes, int n_in,
                              void* d_out, int out_size, void* d_ws, size_t ws_size,
                              hipStream_t stream){
    (void)in_sizes; (void)n_in; (void)out_size;
    const int*   feat  = (const int*)d_in[0];
    const int*   src   = (const int*)d_in[1];
    const int*   dst   = (const int*)d_in[2];
    const float* emb   = (const float*)d_in[3];
    const float* Ws    = (const float*)d_in[4];
    const float* bs    = (const float*)d_in[5];
    const float* gam   = (const float*)d_in[6];
    const float* bet   = (const float*)d_in[7];
    const float* w_out = (const float*)d_in[8];
    const float* b_out = (const float*)d_in[9];
    float* out = (float*)d_out;

    const size_t H_BYTES  = (size_t)NNODE*RANK*2;          // 150,994,944
    const size_t WP_BYTES = (size_t)3*RANK*RANK*2;         // 1,572,864
    const size_t AG_BYTES = (size_t)BGRAPH*81*4;           // 5,308,416
    const size_t NEED     = 2*H_BYTES + WP_BYTES + AG_BYTES;

    if (ws_size >= NEED){
        u16*   hA = (u16*)d_ws;
        u16*   hB = (u16*)((char*)d_ws + H_BYTES);
        u16*   Wp = (u16*)((char*)d_ws + 2*H_BYTES);
        float* Ag = (float*)((char*)d_ws + 2*H_BYTES + WP_BYTES);

        k_repack<<<dim3(3*RANK*RANK/256), dim3(256), 0, stream>>>(Ws, Wp);
        k_prep  <<<dim3(BGRAPH/256),      dim3(256), 0, stream>>>(src, dst, Ag);
        k_embed <<<dim3(NNODE*64/256),    dim3(256), 0, stream>>>(feat, emb, hA);
        k_layer <<<dim3(NNODE/BM), dim3(512), 0, stream>>>(hA, hB, Wp,
            Ag, bs, gam, bet);
        k_layer <<<dim3(NNODE/BM), dim3(512), 0, stream>>>(hB, hA, Wp + (size_t)RANK*RANK,
            Ag, bs+RANK, gam+RANK, bet+RANK);
        k_layer <<<dim3(NNODE/BM), dim3(512), 0, stream>>>(hA, hB, Wp + (size_t)2*RANK*RANK,
            Ag, bs+2*RANK, gam+2*RANK, bet+2*RANK);
        k_out   <<<dim3(BGRAPH/4), dim3(256), 0, stream>>>(hB, w_out, b_out, out);
    } else {
        u16* Wp = (u16*)d_ws;   // 1.5 MB
        k_repack<<<dim3(3*RANK*RANK/256), dim3(256), 0, stream>>>(Ws, Wp);
        k_all<<<dim3(BGRAPH/GPB), dim3(512), 0, stream>>>(feat, src, dst, emb, Wp,
            bs, gam, bet, w_out, b_out, out);
    }
}